// Round 7
// baseline (12373.209 us; speedup 1.0000x reference)
//
#include <hip/hip_runtime.h>
#include <hip/hip_bf16.h>
#include <stdint.h>

typedef uint16_t u16;
typedef uint32_t u32;
typedef unsigned long long u64;
typedef __attribute__((ext_vector_type(8))) short short8;
typedef __attribute__((ext_vector_type(4))) float f32x4;

// B=32, S=1024, D_IN=256, E=512, H=512, F=2048, O=512
#define NS 1024

__device__ __forceinline__ float bf2f(u16 v) {
  union { u32 u; float f; } x; x.u = ((u32)v) << 16; return x.f;
}
__device__ __forceinline__ u16 f2bf(float f) {
  union { float f; u32 u; } x; x.f = f;
  u32 r = x.u + 0x7FFFu + ((x.u >> 16) & 1u);
  return (u16)(r >> 16);
}
__device__ __forceinline__ u32 relu2bf(u32 x) {
  u32 kill = (((x >> 15) & 1u) * 0x0000FFFFu) | (((x >> 31) & 1u) * 0xFFFF0000u);
  return x & ~kill;
}

// ---------------- cast f32 -> bf16 (x4 per thread) ----------------
__global__ __launch_bounds__(256) void k_cast(const float* __restrict__ in,
                                              u16* __restrict__ out, int n4) {
  int i = blockIdx.x * 256 + threadIdx.x;
  if (i >= n4) return;
  float4 v = ((const float4*)in)[i];
  ushort4 o;
  o.x = f2bf(v.x); o.y = f2bf(v.y); o.z = f2bf(v.z); o.w = f2bf(v.w);
  ((ushort4*)out)[i] = o;
}

// ---------------- transpose f32[K][N] -> bf16[N][K] ----------------
__global__ __launch_bounds__(256) void k_transpose(const float* __restrict__ in,
                                                   u16* __restrict__ out,
                                                   int K, int N) {
  __shared__ u16 tile[32][33];
  int k0 = blockIdx.x * 32, n0 = blockIdx.y * 32;
  int tid = threadIdx.x;
#pragma unroll
  for (int i = 0; i < 4; i++) {
    int idx = i * 256 + tid;
    int r = idx >> 5, c = idx & 31;
    tile[r][c] = f2bf(in[(size_t)(k0 + r) * N + n0 + c]);
  }
  __syncthreads();
#pragma unroll
  for (int i = 0; i < 4; i++) {
    int idx = i * 256 + tid;
    int r = idx >> 5, c = idx & 31;
    out[(size_t)(n0 + r) * K + k0 + c] = tile[c][r];
  }
}

// ---------------- bf16 MFMA GEMM: C[M,N] = A[M,K] @ Bt[N,K]^T + bias ----------------
// 128x128 tile, BK=32, 4 waves, each wave 64x64 (4x4 of 16x16x32 MFMA).
// OUTF32: write float, else bf16. REMAP: row b*1024+s -> s*32+b.
template <bool REMAP, bool RELU_A, bool OUTF32>
__global__ __launch_bounds__(256) void k_gemm(const u16* __restrict__ A,
                                              const u16* __restrict__ Bt,
                                              const float* __restrict__ bias,
                                              void* __restrict__ Cout,
                                              int M, int N, int K) {
  __shared__ u16 As[128 * 32];
  __shared__ u16 Bs[128 * 32];
  const int m0 = blockIdx.x * 128, n0 = blockIdx.y * 128;
  const int tid = threadIdx.x;
  const int wave = tid >> 6, lane = tid & 63;
  const int wm = wave >> 1, wn = wave & 1;
  f32x4 acc[4][4] = {};

  for (int kt = 0; kt < K; kt += 32) {
    uint4 av[2], bv[2];
#pragma unroll
    for (int i = 0; i < 2; i++) {
      int idx = i * 256 + tid;
      int r = idx >> 2, ch = idx & 3;   // 4 uint4-chunks per 32-col row
      av[i] = *(const uint4*)(A + (size_t)(m0 + r) * K + kt + ch * 8);
      bv[i] = *(const uint4*)(Bt + (size_t)(n0 + r) * K + kt + ch * 8);
      if (RELU_A) {
        u32* p = (u32*)&av[i];
        p[0] = relu2bf(p[0]); p[1] = relu2bf(p[1]);
        p[2] = relu2bf(p[2]); p[3] = relu2bf(p[3]);
      }
    }
    __syncthreads();
#pragma unroll
    for (int i = 0; i < 2; i++) {
      int idx = i * 256 + tid;
      int r = idx >> 2, ch = idx & 3;
      *(uint4*)(As + r * 32 + ch * 8) = av[i];
      *(uint4*)(Bs + r * 32 + ch * 8) = bv[i];
    }
    __syncthreads();
    short8 af[4], bf[4];
#pragma unroll
    for (int mi = 0; mi < 4; mi++) {
      int row = wm * 64 + mi * 16 + (lane & 15);
      af[mi] = *(const short8*)(As + row * 32 + (lane >> 4) * 8);
    }
#pragma unroll
    for (int ni = 0; ni < 4; ni++) {
      int col = wn * 64 + ni * 16 + (lane & 15);
      bf[ni] = *(const short8*)(Bs + col * 32 + (lane >> 4) * 8);
    }
#pragma unroll
    for (int mi = 0; mi < 4; mi++)
#pragma unroll
      for (int ni = 0; ni < 4; ni++)
        acc[mi][ni] = __builtin_amdgcn_mfma_f32_16x16x32_bf16(af[mi], bf[ni], acc[mi][ni], 0, 0, 0);
  }

#pragma unroll
  for (int mi = 0; mi < 4; mi++)
#pragma unroll
    for (int ni = 0; ni < 4; ni++) {
      int col = n0 + wn * 64 + ni * 16 + (lane & 15);
      float bvad = bias[col];
#pragma unroll
      for (int r = 0; r < 4; r++) {
        int row = m0 + wm * 64 + mi * 16 + (lane >> 4) * 4 + r;
        float v = acc[mi][ni][r] + bvad;
        size_t orow = REMAP ? ((size_t)(row & 1023) * 32 + (size_t)(row >> 10))
                            : (size_t)row;
        if (OUTF32) ((float*)Cout)[orow * N + col] = v;
        else        ((u16*)Cout)[orow * N + col] = f2bf(v);
      }
    }
}

// ---------------- persistent cooperative fused LSTM ----------------
// 64 blocks x 256 threads. Block b owns h-cols [b*8, b*8+8).
// W_ih^T / W_hh^T fragments resident in registers. x@W_ih for step s+1
// computed in the barrier-wait slot of step s. ys/hn/cn stored f32.
__global__ __launch_bounds__(256, 1) void k_lstm(
    const u16* __restrict__ Whh_t,    // [2048][512]
    const u16* __restrict__ Wih_t,    // [2048][512]
    const u16* __restrict__ emb,      // [S*B][512] time-major bf16
    const float* __restrict__ b_lstm, // [2048] f32
    u16* __restrict__ hbuf,           // [2][32][512] zeroed
    float* __restrict__ out,          // [S*B][512] f32 (ys)
    float* __restrict__ hn,
    float* __restrict__ cn,
    unsigned int* __restrict__ cnt)   // zeroed
{
  const int blk = blockIdx.x;
  const int tid = threadIdx.x;
  const int wave = tid >> 6, lane = tid & 63;
  const int hc0 = blk * 8;
  const int mt = wave >> 1, nt = wave & 1;

  // resident B fragments: 16 k-chunks of the wave's 16-col slice, both weights
  short8 bfh[16], bfx[16];
  {
    int lc = nt * 16 + (lane & 15);               // local col 0..31
    int gcol = (lc >> 3) * 512 + hc0 + (lc & 7);  // z column
    const u16* bh = Whh_t + (size_t)gcol * 512 + (lane >> 4) * 8;
    const u16* bx = Wih_t + (size_t)gcol * 512 + (lane >> 4) * 8;
#pragma unroll
    for (int kc = 0; kc < 16; kc++) {
      bfh[kc] = *(const short8*)(bh + kc * 32);
      bfx[kc] = *(const short8*)(bx + kc * 32);
    }
  }

  __shared__ float zt[32][33];
  const int ob = tid >> 3, ojj = tid & 7;  // (batch row, h-col) for gate phase
  const float bi  = b_lstm[hc0 + ojj];
  const float bff = b_lstm[512 + hc0 + ojj];
  const float bg  = b_lstm[1024 + hc0 + ojj];
  const float bo  = b_lstm[1536 + hc0 + ojj];

  float c = 0.f, hval = 0.f;

  // prologue: zx = x_0 @ W_ih for step 0
  f32x4 zx0 = {0.f, 0.f, 0.f, 0.f}, zx1 = {0.f, 0.f, 0.f, 0.f};
  {
    const u16* xb = emb + (size_t)(mt * 16 + (lane & 15)) * 512 + (lane >> 4) * 8;
    short8 af[16];
#pragma unroll
    for (int kc = 0; kc < 16; kc++) af[kc] = *(const short8*)(xb + kc * 32);
#pragma unroll
    for (int kc = 0; kc < 16; kc += 2) {
      zx0 = __builtin_amdgcn_mfma_f32_16x16x32_bf16(af[kc], bfx[kc], zx0, 0, 0, 0);
      zx1 = __builtin_amdgcn_mfma_f32_16x16x32_bf16(af[kc + 1], bfx[kc + 1], zx1, 0, 0, 0);
    }
  }

#pragma unroll 1
  for (int s = 0; s < NS; s++) {
    // A fragments: h_prev rows via agent-scope atomic loads (always coherent)
    const u16* h = hbuf + (size_t)(s & 1) * (32 * 512);
    const u64* ab64 = (const u64*)(h + (size_t)(mt * 16 + (lane & 15)) * 512 + (lane >> 4) * 8);
    short8 afr[16];
#pragma unroll
    for (int kc = 0; kc < 16; kc++) {
      union { short8 s8; u64 q[2]; } t;
      t.q[0] = __hip_atomic_load(ab64 + kc * 8,     __ATOMIC_RELAXED, __HIP_MEMORY_SCOPE_AGENT);
      t.q[1] = __hip_atomic_load(ab64 + kc * 8 + 1, __ATOMIC_RELAXED, __HIP_MEMORY_SCOPE_AGENT);
      afr[kc] = t.s8;
    }

    f32x4 a0 = zx0, a1 = zx1;  // start from pipelined x@W_ih
#pragma unroll
    for (int kc = 0; kc < 16; kc += 2) {
      a0 = __builtin_amdgcn_mfma_f32_16x16x32_bf16(afr[kc], bfh[kc], a0, 0, 0, 0);
      a1 = __builtin_amdgcn_mfma_f32_16x16x32_bf16(afr[kc + 1], bfh[kc + 1], a1, 0, 0, 0);
    }
#pragma unroll
    for (int r = 0; r < 4; r++)
      zt[mt * 16 + (lane >> 4) * 4 + r][nt * 16 + (lane & 15)] = a0[r] + a1[r];
    __syncthreads();

    // gates
    float zi = zt[ob][ojj] + bi;
    float zf = zt[ob][8 + ojj] + bff;
    float zg = zt[ob][16 + ojj] + bg;
    float zo = zt[ob][24 + ojj] + bo;
    float ig = 1.f / (1.f + __expf(-zi));
    float fg = 1.f / (1.f + __expf(-zf));
    float gg = tanhf(zg);
    float og = 1.f / (1.f + __expf(-zo));
    c = fg * c + ig * gg;
    hval = og * tanhf(c);

    out[((size_t)s * 32 + ob) * 512 + hc0 + ojj] = hval;  // f32 output
    // packed bf16 h store via agent-scope atomic (coherent point)
    {
      u16 hb = f2bf(hval);
      u32 nb = (u32)(u16)__shfl_xor((int)hb, 1);
      if ((ojj & 1) == 0) {
        u32 pair = (u32)hb | (nb << 16);
        u32* dst = (u32*)(hbuf + (size_t)((s + 1) & 1) * (32 * 512) + ob * 512 + hc0 + ojj);
        __hip_atomic_store(dst, pair, __ATOMIC_RELAXED, __HIP_MEMORY_SCOPE_AGENT);
      }
    }

    __syncthreads();  // all waves' stores drained before the release add
    if (tid == 0) {
      __threadfence();
      __hip_atomic_fetch_add(cnt, 1u, __ATOMIC_RELEASE, __HIP_MEMORY_SCOPE_AGENT);
    }
    // pipelined zx for step s+1 (independent of h -> hides in barrier wait)
    if (s + 1 < NS) {
      const u16* xb = emb + ((size_t)(s + 1) * 32 + mt * 16 + (lane & 15)) * 512 + (lane >> 4) * 8;
      short8 af2[16];
#pragma unroll
      for (int kc = 0; kc < 16; kc++) af2[kc] = *(const short8*)(xb + kc * 32);
      f32x4 t0 = {0.f, 0.f, 0.f, 0.f}, t1 = {0.f, 0.f, 0.f, 0.f};
#pragma unroll
      for (int kc = 0; kc < 16; kc += 2) {
        t0 = __builtin_amdgcn_mfma_f32_16x16x32_bf16(af2[kc], bfx[kc], t0, 0, 0, 0);
        t1 = __builtin_amdgcn_mfma_f32_16x16x32_bf16(af2[kc + 1], bfx[kc + 1], t1, 0, 0, 0);
      }
      zx0 = t0; zx1 = t1;
    }
    if (tid == 0) {
      unsigned int tgt = 64u * (unsigned)(s + 1);
      while (__hip_atomic_load(cnt, __ATOMIC_ACQUIRE, __HIP_MEMORY_SCOPE_AGENT) < tgt) {}
      __threadfence();
    }
    __syncthreads();
  }

  hn[ob * 512 + hc0 + ojj] = hval;  // f32
  cn[ob * 512 + hc0 + ojj] = c;     // f32
}

extern "C" void kernel_launch(void* const* d_in, const int* in_sizes, int n_in,
                              void* d_out, int out_size, void* d_ws, size_t ws_size,
                              hipStream_t stream) {
  (void)in_sizes; (void)n_in; (void)out_size; (void)ws_size;
  const float* x      = (const float*)d_in[0];
  const float* W_enc  = (const float*)d_in[1];
  const float* b_enc  = (const float*)d_in[2];
  const float* W_ih   = (const float*)d_in[3];
  const float* W_hh   = (const float*)d_in[4];
  const float* b_lstm = (const float*)d_in[5];
  const float* W1     = (const float*)d_in[6];
  const float* b1     = (const float*)d_in[7];
  const float* W2     = (const float*)d_in[8];
  const float* b2     = (const float*)d_in[9];

  char* ws = (char*)d_ws;
  size_t off = 0;
  auto alloc = [&](size_t bytes) -> void* {
    void* p = ws + off;
    off += (bytes + 255) & ~(size_t)255;
    return p;
  };
  // total ws usage: ~40.5 MB
  u16* hbuf   = (u16*)alloc((size_t)2 * 32 * 512 * 2);  // 64 KB h double buffer
  unsigned int* cnt = (unsigned int*)alloc(256);        // barrier counter
  u16* Wenc_t = (u16*)alloc((size_t)512 * 256 * 2);     // [E][DIN]
  u16* Wih_t  = (u16*)alloc((size_t)2048 * 512 * 2);    // [4H][E]
  u16* Whh_t  = (u16*)alloc((size_t)2048 * 512 * 2);    // [4H][H]
  u16* W1_t   = (u16*)alloc((size_t)2048 * 512 * 2);    // [F][E]
  u16* W2_t   = (u16*)alloc((size_t)512 * 2048 * 2);    // [O][F]
  u16* big    = (u16*)alloc((size_t)8192 * 2048 * 2);   // 32 MB union: xbf | T chunk
  u16* xbf    = big;                                    // [B*S][256] (dead before T)
  u16* T      = big;                                    // [8192][2048] fc1 chunk

  // d_out is F32: ys[S*B*H] | h_n[B*H] | c_n[B*H] | embed_out[S*B*O]
  float* outp = (float*)d_out;
  float* hnp  = outp + (size_t)16777216;
  float* cnp  = hnp + 16384;
  float* eop  = cnp + 16384;               // f32 [32768][512]
  // emb (bf16, 33.5 MB) lives in the SECOND HALF of the embed_out region.
  // fc2 chunk c writes f32 bytes [16.78M*c, 16.78M*(c+1)) of the region;
  // fc1 chunk c reads emb bytes [33.55M + 8.39M*c, +8.39M) -- writes never
  // pass reads (16.78M*(c+1) <= 33.55M + 8.39M*(c+1) for c<=3).
  u16* emb  = (u16*)(eop + 8388608);

  // zero h double-buffer + barrier counter (contiguous at ws start)
  hipMemsetAsync(ws, 0, (size_t)2 * 32 * 512 * 2 + 256, stream);

  // convert + transpose weights
  k_cast<<<8192, 256, 0, stream>>>(x, xbf, 2097152);
  k_transpose<<<dim3(8, 16), 256, 0, stream>>>(W_enc, Wenc_t, 256, 512);
  k_transpose<<<dim3(16, 64), 256, 0, stream>>>(W_ih, Wih_t, 512, 2048);
  k_transpose<<<dim3(16, 64), 256, 0, stream>>>(W_hh, Whh_t, 512, 2048);
  k_transpose<<<dim3(16, 64), 256, 0, stream>>>(W1, W1_t, 512, 2048);
  k_transpose<<<dim3(64, 16), 256, 0, stream>>>(W2, W2_t, 2048, 512);

  // encoder: emb[s*32+b][E] = x@W_enc + b_enc  (bf16 out, row remap)
  k_gemm<true, false, false><<<dim3(256, 4), 256, 0, stream>>>(
      xbf, Wenc_t, b_enc, emb, 32768, 512, 256);

  // recurrence (cooperative; fused x@W_ih, software-pipelined; f32 outputs)
  {
    void* args[] = {(void*)&Whh_t, (void*)&Wih_t, (void*)&emb, (void*)&b_lstm,
                    (void*)&hbuf, (void*)&outp, (void*)&hnp, (void*)&cnp, (void*)&cnt};
    hipLaunchCooperativeKernel((const void*)k_lstm, dim3(64), dim3(256), args, 0, stream);
  }

  // MLP in 4 chunks of 8192 rows: fc1 -> T (bf16, ws), fc2 -> embed_out (f32)
  for (int cch = 0; cch < 4; cch++) {
    const u16* embc = emb + (size_t)cch * 8192 * 512;
    float* eoc = eop + (size_t)cch * 8192 * 512;
    k_gemm<false, true, false><<<dim3(64, 16), 256, 0, stream>>>(
        embc, W1_t, b1, T, 8192, 2048, 512);
    k_gemm<false, false, true><<<dim3(64, 4), 256, 0, stream>>>(
        T, W2_t, b2, eoc, 8192, 512, 2048);
  }
}

// Round 8
// 8423.614 us; speedup vs baseline: 1.4689x; 1.4689x over previous
//
#include <hip/hip_runtime.h>
#include <hip/hip_bf16.h>
#include <stdint.h>

typedef uint16_t u16;
typedef uint32_t u32;
typedef unsigned long long u64;
typedef __attribute__((ext_vector_type(8))) short short8;
typedef __attribute__((ext_vector_type(4))) float f32x4;

// B=32, S=1024, D_IN=256, E=512, H=512, F=2048, O=512
#define NS 1024

__device__ __forceinline__ float bf2f(u16 v) {
  union { u32 u; float f; } x; x.u = ((u32)v) << 16; return x.f;
}
__device__ __forceinline__ u16 f2bf(float f) {
  union { float f; u32 u; } x; x.f = f;
  u32 r = x.u + 0x7FFFu + ((x.u >> 16) & 1u);
  return (u16)(r >> 16);
}
__device__ __forceinline__ u32 relu2bf(u32 x) {
  u32 kill = (((x >> 15) & 1u) * 0x0000FFFFu) | (((x >> 31) & 1u) * 0xFFFF0000u);
  return x & ~kill;
}

// ---------------- cast f32 -> bf16 (x4 per thread) ----------------
__global__ __launch_bounds__(256) void k_cast(const float* __restrict__ in,
                                              u16* __restrict__ out, int n4) {
  int i = blockIdx.x * 256 + threadIdx.x;
  if (i >= n4) return;
  float4 v = ((const float4*)in)[i];
  ushort4 o;
  o.x = f2bf(v.x); o.y = f2bf(v.y); o.z = f2bf(v.z); o.w = f2bf(v.w);
  ((ushort4*)out)[i] = o;
}

// ---------------- transpose f32[K][N] -> bf16[N][K] ----------------
__global__ __launch_bounds__(256) void k_transpose(const float* __restrict__ in,
                                                   u16* __restrict__ out,
                                                   int K, int N) {
  __shared__ u16 tile[32][33];
  int k0 = blockIdx.x * 32, n0 = blockIdx.y * 32;
  int tid = threadIdx.x;
#pragma unroll
  for (int i = 0; i < 4; i++) {
    int idx = i * 256 + tid;
    int r = idx >> 5, c = idx & 31;
    tile[r][c] = f2bf(in[(size_t)(k0 + r) * N + n0 + c]);
  }
  __syncthreads();
#pragma unroll
  for (int i = 0; i < 4; i++) {
    int idx = i * 256 + tid;
    int r = idx >> 5, c = idx & 31;
    out[(size_t)(n0 + r) * K + k0 + c] = tile[c][r];
  }
}

// ---------------- bf16 MFMA GEMM: C[M,N] = A[M,K] @ Bt[N,K]^T + bias ----------------
// 128x128 tile, BK=32, 4 waves, each wave 64x64 (4x4 of 16x16x32 MFMA).
// OUTF32: write float, else bf16. REMAP: row b*1024+s -> s*32+b.
template <bool REMAP, bool RELU_A, bool OUTF32>
__global__ __launch_bounds__(256) void k_gemm(const u16* __restrict__ A,
                                              const u16* __restrict__ Bt,
                                              const float* __restrict__ bias,
                                              void* __restrict__ Cout,
                                              int M, int N, int K) {
  __shared__ u16 As[128 * 32];
  __shared__ u16 Bs[128 * 32];
  const int m0 = blockIdx.x * 128, n0 = blockIdx.y * 128;
  const int tid = threadIdx.x;
  const int wave = tid >> 6, lane = tid & 63;
  const int wm = wave >> 1, wn = wave & 1;
  f32x4 acc[4][4] = {};

  for (int kt = 0; kt < K; kt += 32) {
    uint4 av[2], bv[2];
#pragma unroll
    for (int i = 0; i < 2; i++) {
      int idx = i * 256 + tid;
      int r = idx >> 2, ch = idx & 3;   // 4 uint4-chunks per 32-col row
      av[i] = *(const uint4*)(A + (size_t)(m0 + r) * K + kt + ch * 8);
      bv[i] = *(const uint4*)(Bt + (size_t)(n0 + r) * K + kt + ch * 8);
      if (RELU_A) {
        u32* p = (u32*)&av[i];
        p[0] = relu2bf(p[0]); p[1] = relu2bf(p[1]);
        p[2] = relu2bf(p[2]); p[3] = relu2bf(p[3]);
      }
    }
    __syncthreads();
#pragma unroll
    for (int i = 0; i < 2; i++) {
      int idx = i * 256 + tid;
      int r = idx >> 2, ch = idx & 3;
      *(uint4*)(As + r * 32 + ch * 8) = av[i];
      *(uint4*)(Bs + r * 32 + ch * 8) = bv[i];
    }
    __syncthreads();
    short8 af[4], bf[4];
#pragma unroll
    for (int mi = 0; mi < 4; mi++) {
      int row = wm * 64 + mi * 16 + (lane & 15);
      af[mi] = *(const short8*)(As + row * 32 + (lane >> 4) * 8);
    }
#pragma unroll
    for (int ni = 0; ni < 4; ni++) {
      int col = wn * 64 + ni * 16 + (lane & 15);
      bf[ni] = *(const short8*)(Bs + col * 32 + (lane >> 4) * 8);
    }
#pragma unroll
    for (int mi = 0; mi < 4; mi++)
#pragma unroll
      for (int ni = 0; ni < 4; ni++)
        acc[mi][ni] = __builtin_amdgcn_mfma_f32_16x16x32_bf16(af[mi], bf[ni], acc[mi][ni], 0, 0, 0);
  }

#pragma unroll
  for (int mi = 0; mi < 4; mi++)
#pragma unroll
    for (int ni = 0; ni < 4; ni++) {
      int col = n0 + wn * 64 + ni * 16 + (lane & 15);
      float bvad = bias[col];
#pragma unroll
      for (int r = 0; r < 4; r++) {
        int row = m0 + wm * 64 + mi * 16 + (lane >> 4) * 4 + r;
        float v = acc[mi][ni][r] + bvad;
        size_t orow = REMAP ? ((size_t)(row & 1023) * 32 + (size_t)(row >> 10))
                            : (size_t)row;
        if (OUTF32) ((float*)Cout)[orow * N + col] = v;
        else        ((u16*)Cout)[orow * N + col] = f2bf(v);
      }
    }
}

// ---------------- persistent cooperative fused LSTM ----------------
// 64 blocks x 256 threads. Block b owns h-cols [b*8, b*8+8).
// W_ih^T / W_hh^T fragments resident in registers. x@W_ih for step s+1
// computed between barrier-arrival and barrier-wait (hides propagation).
// Barrier: per-block FLAG lines (no RMW contention, no threadfence);
// h payload via agent-scope atomics (coherent by construction).
__global__ __launch_bounds__(256, 1) void k_lstm(
    const u16* __restrict__ Whh_t,    // [2048][512]
    const u16* __restrict__ Wih_t,    // [2048][512]
    const u16* __restrict__ emb,      // [S*B][512] time-major bf16
    const float* __restrict__ b_lstm, // [2048] f32
    u16* __restrict__ hbuf,           // [2][32][512] zeroed
    float* __restrict__ out,          // [S*B][512] f32 (ys)
    float* __restrict__ hn,
    float* __restrict__ cn,
    u32* __restrict__ flags)          // [64 * 32] zeroed, 128B stride
{
  const int blk = blockIdx.x;
  const int tid = threadIdx.x;
  const int wave = tid >> 6, lane = tid & 63;
  const int hc0 = blk * 8;
  const int mt = wave >> 1, nt = wave & 1;

  // resident B fragments: 16 k-chunks of the wave's 16-col slice, both weights
  short8 bfh[16], bfx[16];
  {
    int lc = nt * 16 + (lane & 15);               // local col 0..31
    int gcol = (lc >> 3) * 512 + hc0 + (lc & 7);  // z column
    const u16* bh = Whh_t + (size_t)gcol * 512 + (lane >> 4) * 8;
    const u16* bx = Wih_t + (size_t)gcol * 512 + (lane >> 4) * 8;
#pragma unroll
    for (int kc = 0; kc < 16; kc++) {
      bfh[kc] = *(const short8*)(bh + kc * 32);
      bfx[kc] = *(const short8*)(bx + kc * 32);
    }
  }

  __shared__ float zt[32][33];
  const int ob = tid >> 3, ojj = tid & 7;  // (batch row, h-col) for gate phase
  const float bi  = b_lstm[hc0 + ojj];
  const float bff = b_lstm[512 + hc0 + ojj];
  const float bg  = b_lstm[1024 + hc0 + ojj];
  const float bo  = b_lstm[1536 + hc0 + ojj];

  float c = 0.f, hval = 0.f;

  // prologue: zx = x_0 @ W_ih for step 0
  f32x4 zx0 = {0.f, 0.f, 0.f, 0.f}, zx1 = {0.f, 0.f, 0.f, 0.f};
  {
    const u16* xb = emb + (size_t)(mt * 16 + (lane & 15)) * 512 + (lane >> 4) * 8;
    short8 af[16];
#pragma unroll
    for (int kc = 0; kc < 16; kc++) af[kc] = *(const short8*)(xb + kc * 32);
#pragma unroll
    for (int kc = 0; kc < 16; kc += 2) {
      zx0 = __builtin_amdgcn_mfma_f32_16x16x32_bf16(af[kc], bfx[kc], zx0, 0, 0, 0);
      zx1 = __builtin_amdgcn_mfma_f32_16x16x32_bf16(af[kc + 1], bfx[kc + 1], zx1, 0, 0, 0);
    }
  }

#pragma unroll 1
  for (int s = 0; s < NS; s++) {
    // A fragments: h_prev rows via agent-scope atomic loads (always coherent)
    const u16* h = hbuf + (size_t)(s & 1) * (32 * 512);
    const u64* ab64 = (const u64*)(h + (size_t)(mt * 16 + (lane & 15)) * 512 + (lane >> 4) * 8);
    short8 afr[16];
#pragma unroll
    for (int kc = 0; kc < 16; kc++) {
      union { short8 s8; u64 q[2]; } t;
      t.q[0] = __hip_atomic_load(ab64 + kc * 8,     __ATOMIC_RELAXED, __HIP_MEMORY_SCOPE_AGENT);
      t.q[1] = __hip_atomic_load(ab64 + kc * 8 + 1, __ATOMIC_RELAXED, __HIP_MEMORY_SCOPE_AGENT);
      afr[kc] = t.s8;
    }

    f32x4 a0 = zx0, a1 = zx1;  // start from pipelined x@W_ih
#pragma unroll
    for (int kc = 0; kc < 16; kc += 2) {
      a0 = __builtin_amdgcn_mfma_f32_16x16x32_bf16(afr[kc], bfh[kc], a0, 0, 0, 0);
      a1 = __builtin_amdgcn_mfma_f32_16x16x32_bf16(afr[kc + 1], bfh[kc + 1], a1, 0, 0, 0);
    }
#pragma unroll
    for (int r = 0; r < 4; r++)
      zt[mt * 16 + (lane >> 4) * 4 + r][nt * 16 + (lane & 15)] = a0[r] + a1[r];
    __syncthreads();

    // gates
    float zi = zt[ob][ojj] + bi;
    float zf = zt[ob][8 + ojj] + bff;
    float zg = zt[ob][16 + ojj] + bg;
    float zo = zt[ob][24 + ojj] + bo;
    float ig = 1.f / (1.f + __expf(-zi));
    float fg = 1.f / (1.f + __expf(-zf));
    float gg = tanhf(zg);
    float og = 1.f / (1.f + __expf(-zo));
    c = fg * c + ig * gg;
    hval = og * tanhf(c);

    out[((size_t)s * 32 + ob) * 512 + hc0 + ojj] = hval;  // f32 output
    // packed bf16 h store via agent-scope atomic (coherent point)
    {
      u16 hb = f2bf(hval);
      u32 nb = (u32)(u16)__shfl_xor((int)hb, 1);
      if ((ojj & 1) == 0) {
        u32 pair = (u32)hb | (nb << 16);
        u32* dst = (u32*)(hbuf + (size_t)((s + 1) & 1) * (32 * 512) + ob * 512 + hc0 + ojj);
        __hip_atomic_store(dst, pair, __ATOMIC_RELAXED, __HIP_MEMORY_SCOPE_AGENT);
      }
    }

    // __syncthreads drains each wave's vmcnt to 0 before s_barrier
    // [HIP-compiler] -> all h atomic stores are at the coherence point.
    __syncthreads();
    if (tid == 0)
      __hip_atomic_store(flags + (size_t)blk * 32, (u32)(s + 1),
                         __ATOMIC_RELAXED, __HIP_MEMORY_SCOPE_AGENT);

    // pipelined zx for step s+1 (independent of h -> hides flag propagation)
    if (s + 1 < NS) {
      const u16* xb = emb + ((size_t)(s + 1) * 32 + mt * 16 + (lane & 15)) * 512 + (lane >> 4) * 8;
      short8 af2[16];
#pragma unroll
      for (int kc = 0; kc < 16; kc++) af2[kc] = *(const short8*)(xb + kc * 32);
      f32x4 t0 = {0.f, 0.f, 0.f, 0.f}, t1 = {0.f, 0.f, 0.f, 0.f};
#pragma unroll
      for (int kc = 0; kc < 16; kc += 2) {
        t0 = __builtin_amdgcn_mfma_f32_16x16x32_bf16(af2[kc], bfx[kc], t0, 0, 0, 0);
        t1 = __builtin_amdgcn_mfma_f32_16x16x32_bf16(af2[kc + 1], bfx[kc + 1], t1, 0, 0, 0);
      }
      zx0 = t0; zx1 = t1;
    }

    // wait: 64 lanes poll 64 distinct flag lines in parallel (no contention)
    if (tid < 64) {
      const u32* f = flags + (size_t)tid * 32;
      u32 tgt = (u32)(s + 1);
      while (__hip_atomic_load(f, __ATOMIC_RELAXED, __HIP_MEMORY_SCOPE_AGENT) < tgt)
        __builtin_amdgcn_s_sleep(1);
    }
    __syncthreads();
  }

  hn[ob * 512 + hc0 + ojj] = hval;  // f32
  cn[ob * 512 + hc0 + ojj] = c;     // f32
}

extern "C" void kernel_launch(void* const* d_in, const int* in_sizes, int n_in,
                              void* d_out, int out_size, void* d_ws, size_t ws_size,
                              hipStream_t stream) {
  (void)in_sizes; (void)n_in; (void)out_size; (void)ws_size;
  const float* x      = (const float*)d_in[0];
  const float* W_enc  = (const float*)d_in[1];
  const float* b_enc  = (const float*)d_in[2];
  const float* W_ih   = (const float*)d_in[3];
  const float* W_hh   = (const float*)d_in[4];
  const float* b_lstm = (const float*)d_in[5];
  const float* W1     = (const float*)d_in[6];
  const float* b1     = (const float*)d_in[7];
  const float* W2     = (const float*)d_in[8];
  const float* b2     = (const float*)d_in[9];

  char* ws = (char*)d_ws;
  size_t off = 0;
  auto alloc = [&](size_t bytes) -> void* {
    void* p = ws + off;
    off += (bytes + 255) & ~(size_t)255;
    return p;
  };
  // total ws usage: ~40.5 MB
  u16* hbuf   = (u16*)alloc((size_t)2 * 32 * 512 * 2);  // 64 KB h double buffer
  u32* flags  = (u32*)alloc((size_t)64 * 128);          // 8 KB flag lines
  u16* Wenc_t = (u16*)alloc((size_t)512 * 256 * 2);     // [E][DIN]
  u16* Wih_t  = (u16*)alloc((size_t)2048 * 512 * 2);    // [4H][E]
  u16* Whh_t  = (u16*)alloc((size_t)2048 * 512 * 2);    // [4H][H]
  u16* W1_t   = (u16*)alloc((size_t)2048 * 512 * 2);    // [F][E]
  u16* W2_t   = (u16*)alloc((size_t)512 * 2048 * 2);    // [O][F]
  u16* big    = (u16*)alloc((size_t)8192 * 2048 * 2);   // 32 MB union: xbf | T chunk
  u16* xbf    = big;                                    // [B*S][256] (dead before T)
  u16* T      = big;                                    // [8192][2048] fc1 chunk

  // d_out is F32: ys[S*B*H] | h_n[B*H] | c_n[B*H] | embed_out[S*B*O]
  float* outp = (float*)d_out;
  float* hnp  = outp + (size_t)16777216;
  float* cnp  = hnp + 16384;
  float* eop  = cnp + 16384;               // f32 [32768][512]
  // emb (bf16, 33.5 MB) lives in the SECOND HALF of the embed_out region.
  // fc2 chunk c writes f32 bytes [16.78M*c, 16.78M*(c+1)) of the region;
  // fc1 chunk c reads emb bytes [33.55M + 8.39M*c, +8.39M) -- writes never
  // pass reads (16.78M*(c+1) <= 33.55M + 8.39M*(c+1) for c<=3).
  u16* emb  = (u16*)(eop + 8388608);

  // zero h double-buffer + flags (contiguous at ws start)
  hipMemsetAsync(ws, 0, (size_t)2 * 32 * 512 * 2 + (size_t)64 * 128, stream);

  // convert + transpose weights
  k_cast<<<8192, 256, 0, stream>>>(x, xbf, 2097152);
  k_transpose<<<dim3(8, 16), 256, 0, stream>>>(W_enc, Wenc_t, 256, 512);
  k_transpose<<<dim3(16, 64), 256, 0, stream>>>(W_ih, Wih_t, 512, 2048);
  k_transpose<<<dim3(16, 64), 256, 0, stream>>>(W_hh, Whh_t, 512, 2048);
  k_transpose<<<dim3(16, 64), 256, 0, stream>>>(W1, W1_t, 512, 2048);
  k_transpose<<<dim3(64, 16), 256, 0, stream>>>(W2, W2_t, 2048, 512);

  // encoder: emb[s*32+b][E] = x@W_enc + b_enc  (bf16 out, row remap)
  k_gemm<true, false, false><<<dim3(256, 4), 256, 0, stream>>>(
      xbf, Wenc_t, b_enc, emb, 32768, 512, 256);

  // recurrence (cooperative; fused x@W_ih, software-pipelined; f32 outputs)
  {
    void* args[] = {(void*)&Whh_t, (void*)&Wih_t, (void*)&emb, (void*)&b_lstm,
                    (void*)&hbuf, (void*)&outp, (void*)&hnp, (void*)&cnp, (void*)&flags};
    hipLaunchCooperativeKernel((const void*)k_lstm, dim3(64), dim3(256), args, 0, stream);
  }

  // MLP in 4 chunks of 8192 rows: fc1 -> T (bf16, ws), fc2 -> embed_out (f32)
  for (int cch = 0; cch < 4; cch++) {
    const u16* embc = emb + (size_t)cch * 8192 * 512;
    float* eoc = eop + (size_t)cch * 8192 * 512;
    k_gemm<false, true, false><<<dim3(64, 16), 256, 0, stream>>>(
        embc, W1_t, b1, T, 8192, 2048, 512);
    k_gemm<false, false, true><<<dim3(64, 4), 256, 0, stream>>>(
        T, W2_t, b2, eoc, 8192, 512, 2048);
  }
}

// Round 9
// 8076.973 us; speedup vs baseline: 1.5319x; 1.0429x over previous
//
#include <hip/hip_runtime.h>
#include <hip/hip_bf16.h>
#include <stdint.h>

typedef uint16_t u16;
typedef uint32_t u32;
typedef unsigned long long u64;
typedef __attribute__((ext_vector_type(8))) short short8;
typedef __attribute__((ext_vector_type(4))) float f32x4;

// B=32, S=1024, D_IN=256, E=512, H=512, F=2048, O=512
#define NS 1024

__device__ __forceinline__ float bf2f(u16 v) {
  union { u32 u; float f; } x; x.u = ((u32)v) << 16; return x.f;
}
__device__ __forceinline__ u16 f2bf(float f) {
  union { float f; u32 u; } x; x.f = f;
  u32 r = x.u + 0x7FFFu + ((x.u >> 16) & 1u);
  return (u16)(r >> 16);
}
__device__ __forceinline__ u32 relu2bf(u32 x) {
  u32 kill = (((x >> 15) & 1u) * 0x0000FFFFu) | (((x >> 31) & 1u) * 0xFFFF0000u);
  return x & ~kill;
}

// ---------------- cast f32 -> bf16 (x4 per thread) ----------------
__global__ __launch_bounds__(256) void k_cast(const float* __restrict__ in,
                                              u16* __restrict__ out, int n4) {
  int i = blockIdx.x * 256 + threadIdx.x;
  if (i >= n4) return;
  float4 v = ((const float4*)in)[i];
  ushort4 o;
  o.x = f2bf(v.x); o.y = f2bf(v.y); o.z = f2bf(v.z); o.w = f2bf(v.w);
  ((ushort4*)out)[i] = o;
}

// ---------------- transpose f32[K][N] -> bf16[N][K] ----------------
__global__ __launch_bounds__(256) void k_transpose(const float* __restrict__ in,
                                                   u16* __restrict__ out,
                                                   int K, int N) {
  __shared__ u16 tile[32][33];
  int k0 = blockIdx.x * 32, n0 = blockIdx.y * 32;
  int tid = threadIdx.x;
#pragma unroll
  for (int i = 0; i < 4; i++) {
    int idx = i * 256 + tid;
    int r = idx >> 5, c = idx & 31;
    tile[r][c] = f2bf(in[(size_t)(k0 + r) * N + n0 + c]);
  }
  __syncthreads();
#pragma unroll
  for (int i = 0; i < 4; i++) {
    int idx = i * 256 + tid;
    int r = idx >> 5, c = idx & 31;
    out[(size_t)(n0 + r) * K + k0 + c] = tile[c][r];
  }
}

// ---------------- bf16 MFMA GEMM: C[M,N] = A[M,K] @ Bt[N,K]^T + bias ----------------
// 128x128 tile, BK=32, 4 waves, each wave 64x64 (4x4 of 16x16x32 MFMA).
// OUTF32: write float, else bf16. REMAP: row b*1024+s -> s*32+b.
template <bool REMAP, bool RELU_A, bool OUTF32>
__global__ __launch_bounds__(256) void k_gemm(const u16* __restrict__ A,
                                              const u16* __restrict__ Bt,
                                              const float* __restrict__ bias,
                                              void* __restrict__ Cout,
                                              int M, int N, int K) {
  __shared__ u16 As[128 * 32];
  __shared__ u16 Bs[128 * 32];
  const int m0 = blockIdx.x * 128, n0 = blockIdx.y * 128;
  const int tid = threadIdx.x;
  const int wave = tid >> 6, lane = tid & 63;
  const int wm = wave >> 1, wn = wave & 1;
  f32x4 acc[4][4] = {};

  for (int kt = 0; kt < K; kt += 32) {
    uint4 av[2], bv[2];
#pragma unroll
    for (int i = 0; i < 2; i++) {
      int idx = i * 256 + tid;
      int r = idx >> 2, ch = idx & 3;   // 4 uint4-chunks per 32-col row
      av[i] = *(const uint4*)(A + (size_t)(m0 + r) * K + kt + ch * 8);
      bv[i] = *(const uint4*)(Bt + (size_t)(n0 + r) * K + kt + ch * 8);
      if (RELU_A) {
        u32* p = (u32*)&av[i];
        p[0] = relu2bf(p[0]); p[1] = relu2bf(p[1]);
        p[2] = relu2bf(p[2]); p[3] = relu2bf(p[3]);
      }
    }
    __syncthreads();
#pragma unroll
    for (int i = 0; i < 2; i++) {
      int idx = i * 256 + tid;
      int r = idx >> 2, ch = idx & 3;
      *(uint4*)(As + r * 32 + ch * 8) = av[i];
      *(uint4*)(Bs + r * 32 + ch * 8) = bv[i];
    }
    __syncthreads();
    short8 af[4], bf[4];
#pragma unroll
    for (int mi = 0; mi < 4; mi++) {
      int row = wm * 64 + mi * 16 + (lane & 15);
      af[mi] = *(const short8*)(As + row * 32 + (lane >> 4) * 8);
    }
#pragma unroll
    for (int ni = 0; ni < 4; ni++) {
      int col = wn * 64 + ni * 16 + (lane & 15);
      bf[ni] = *(const short8*)(Bs + col * 32 + (lane >> 4) * 8);
    }
#pragma unroll
    for (int mi = 0; mi < 4; mi++)
#pragma unroll
      for (int ni = 0; ni < 4; ni++)
        acc[mi][ni] = __builtin_amdgcn_mfma_f32_16x16x32_bf16(af[mi], bf[ni], acc[mi][ni], 0, 0, 0);
  }

#pragma unroll
  for (int mi = 0; mi < 4; mi++)
#pragma unroll
    for (int ni = 0; ni < 4; ni++) {
      int col = n0 + wn * 64 + ni * 16 + (lane & 15);
      float bvad = bias[col];
#pragma unroll
      for (int r = 0; r < 4; r++) {
        int row = m0 + wm * 64 + mi * 16 + (lane >> 4) * 4 + r;
        float v = acc[mi][ni][r] + bvad;
        size_t orow = REMAP ? ((size_t)(row & 1023) * 32 + (size_t)(row >> 10))
                            : (size_t)row;
        if (OUTF32) ((float*)Cout)[orow * N + col] = v;
        else        ((u16*)Cout)[orow * N + col] = f2bf(v);
      }
    }
}

// ---------------- persistent cooperative fused LSTM ----------------
// 64 blocks x 256 threads. Block b owns h-cols [b*8, b*8+8).
// Critical-path design (per step):
//   [issue emb loads for s+1]  <- overlap with h-load latency
//   [issue h atomic loads] -> MFMA -> zt -> gates
//   h atomic store -> syncthreads (vmcnt drain) -> flag store
//   ys store (deferred; drains during poll) + zx MFMA (register-only)
//   per-wave 64-lane flag poll (no trailing block barrier)
__global__ __launch_bounds__(256, 1) void k_lstm(
    const u16* __restrict__ Whh_t,    // [2048][512]
    const u16* __restrict__ Wih_t,    // [2048][512]
    const u16* __restrict__ emb,      // [S*B][512] time-major bf16
    const float* __restrict__ b_lstm, // [2048] f32
    u16* __restrict__ hbuf,           // [2][32][512] zeroed
    float* __restrict__ out,          // [S*B][512] f32 (ys)
    float* __restrict__ hn,
    float* __restrict__ cn,
    u32* __restrict__ flags)          // [64 * 32] zeroed, 128B stride
{
  const int blk = blockIdx.x;
  const int tid = threadIdx.x;
  const int wave = tid >> 6, lane = tid & 63;
  const int hc0 = blk * 8;
  const int mt = wave >> 1, nt = wave & 1;

  // resident B fragments: 16 k-chunks of the wave's 16-col slice, both weights
  short8 bfh[16], bfx[16];
  {
    int lc = nt * 16 + (lane & 15);               // local col 0..31
    int gcol = (lc >> 3) * 512 + hc0 + (lc & 7);  // z column
    const u16* bh = Whh_t + (size_t)gcol * 512 + (lane >> 4) * 8;
    const u16* bx = Wih_t + (size_t)gcol * 512 + (lane >> 4) * 8;
#pragma unroll
    for (int kc = 0; kc < 16; kc++) {
      bfh[kc] = *(const short8*)(bh + kc * 32);
      bfx[kc] = *(const short8*)(bx + kc * 32);
    }
  }

  __shared__ float zt[32][33];
  const int ob = tid >> 3, ojj = tid & 7;  // (batch row, h-col) for gate phase
  const float bi  = b_lstm[hc0 + ojj];
  const float bff = b_lstm[512 + hc0 + ojj];
  const float bg  = b_lstm[1024 + hc0 + ojj];
  const float bo  = b_lstm[1536 + hc0 + ojj];

  float c = 0.f, hval = 0.f;

  // prologue: zx = x_0 @ W_ih for step 0
  f32x4 zx0 = {0.f, 0.f, 0.f, 0.f}, zx1 = {0.f, 0.f, 0.f, 0.f};
  {
    const u16* xb = emb + (size_t)(mt * 16 + (lane & 15)) * 512 + (lane >> 4) * 8;
    short8 af[16];
#pragma unroll
    for (int kc = 0; kc < 16; kc++) af[kc] = *(const short8*)(xb + kc * 32);
#pragma unroll
    for (int kc = 0; kc < 16; kc += 2) {
      zx0 = __builtin_amdgcn_mfma_f32_16x16x32_bf16(af[kc], bfx[kc], zx0, 0, 0, 0);
      zx1 = __builtin_amdgcn_mfma_f32_16x16x32_bf16(af[kc + 1], bfx[kc + 1], zx1, 0, 0, 0);
    }
  }

#pragma unroll 1
  for (int s = 0; s < NS; s++) {
    // ---- prefetch emb for step s+1 FIRST (overlaps h-load latency) ----
    int sp = (s + 1 < NS) ? (s + 1) : s;   // clamp (last iter value unused)
    const u16* xb = emb + ((size_t)sp * 32 + mt * 16 + (lane & 15)) * 512 + (lane >> 4) * 8;
    short8 af2[16];
#pragma unroll
    for (int kc = 0; kc < 16; kc++) af2[kc] = *(const short8*)(xb + kc * 32);

    // ---- h_prev fragments via agent-scope atomic loads (coherent) ----
    const u16* h = hbuf + (size_t)(s & 1) * (32 * 512);
    const u64* ab64 = (const u64*)(h + (size_t)(mt * 16 + (lane & 15)) * 512 + (lane >> 4) * 8);
    short8 afr[16];
#pragma unroll
    for (int kc = 0; kc < 16; kc++) {
      union { short8 s8; u64 q[2]; } t;
      t.q[0] = __hip_atomic_load(ab64 + kc * 8,     __ATOMIC_RELAXED, __HIP_MEMORY_SCOPE_AGENT);
      t.q[1] = __hip_atomic_load(ab64 + kc * 8 + 1, __ATOMIC_RELAXED, __HIP_MEMORY_SCOPE_AGENT);
      afr[kc] = t.s8;
    }

    f32x4 a0 = zx0, a1 = zx1;  // start from pipelined x@W_ih
#pragma unroll
    for (int kc = 0; kc < 16; kc += 2) {
      a0 = __builtin_amdgcn_mfma_f32_16x16x32_bf16(afr[kc], bfh[kc], a0, 0, 0, 0);
      a1 = __builtin_amdgcn_mfma_f32_16x16x32_bf16(afr[kc + 1], bfh[kc + 1], a1, 0, 0, 0);
    }
#pragma unroll
    for (int r = 0; r < 4; r++)
      zt[mt * 16 + (lane >> 4) * 4 + r][nt * 16 + (lane & 15)] = a0[r] + a1[r];
    __syncthreads();

    // gates
    float zi = zt[ob][ojj] + bi;
    float zf = zt[ob][8 + ojj] + bff;
    float zg = zt[ob][16 + ojj] + bg;
    float zo = zt[ob][24 + ojj] + bo;
    float ig = 1.f / (1.f + __expf(-zi));
    float fg = 1.f / (1.f + __expf(-zf));
    float gg = tanhf(zg);
    float og = 1.f / (1.f + __expf(-zo));
    c = fg * c + ig * gg;
    hval = og * tanhf(c);

    // packed bf16 h store via agent-scope atomic (coherent point)
    u16 hb = f2bf(hval);
    {
      u32 nb = (u32)(u16)__shfl_xor((int)hb, 1);
      if ((ojj & 1) == 0) {
        u32 pair = (u32)hb | (nb << 16);
        u32* dst = (u32*)(hbuf + (size_t)((s + 1) & 1) * (32 * 512) + ob * 512 + hc0 + ojj);
        __hip_atomic_store(dst, pair, __ATOMIC_RELAXED, __HIP_MEMORY_SCOPE_AGENT);
      }
    }

    // __syncthreads drains each wave's vmcnt to 0 before s_barrier
    // [HIP-compiler] -> all h atomic stores at coherence point; emb
    // prefetch loads (issued first) are long complete.
    __syncthreads();
    if (tid == 0)
      __hip_atomic_store(flags + (size_t)blk * 32, (u32)(s + 1),
                         __ATOMIC_RELAXED, __HIP_MEMORY_SCOPE_AGENT);

    // deferred ys store (not part of inter-block contract; drains later)
    out[((size_t)s * 32 + ob) * 512 + hc0 + ojj] = hval;

    // register-only zx for step s+1 (~30ns; no memory on critical path)
    if (s + 1 < NS) {
      f32x4 t0 = {0.f, 0.f, 0.f, 0.f}, t1 = {0.f, 0.f, 0.f, 0.f};
#pragma unroll
      for (int kc = 0; kc < 16; kc += 2) {
        t0 = __builtin_amdgcn_mfma_f32_16x16x32_bf16(af2[kc], bfx[kc], t0, 0, 0, 0);
        t1 = __builtin_amdgcn_mfma_f32_16x16x32_bf16(af2[kc + 1], bfx[kc + 1], t1, 0, 0, 0);
      }
      zx0 = t0; zx1 = t1;
    }

    // per-wave poll: lane l polls flag l; wave proceeds when all 64 set.
    // No trailing block barrier needed (zt reads all happened before the
    // pre-flag syncthreads; zt writes of s+1 happen after this poll).
    {
      const u32* f = flags + (size_t)lane * 32;
      u32 tgt = (u32)(s + 1);
      while (true) {
        u32 v = __hip_atomic_load(f, __ATOMIC_RELAXED, __HIP_MEMORY_SCOPE_AGENT);
        if (__all(v >= tgt)) break;
        __builtin_amdgcn_s_sleep(1);
      }
    }
  }

  hn[ob * 512 + hc0 + ojj] = hval;  // f32
  cn[ob * 512 + hc0 + ojj] = c;     // f32
}

extern "C" void kernel_launch(void* const* d_in, const int* in_sizes, int n_in,
                              void* d_out, int out_size, void* d_ws, size_t ws_size,
                              hipStream_t stream) {
  (void)in_sizes; (void)n_in; (void)out_size; (void)ws_size;
  const float* x      = (const float*)d_in[0];
  const float* W_enc  = (const float*)d_in[1];
  const float* b_enc  = (const float*)d_in[2];
  const float* W_ih   = (const float*)d_in[3];
  const float* W_hh   = (const float*)d_in[4];
  const float* b_lstm = (const float*)d_in[5];
  const float* W1     = (const float*)d_in[6];
  const float* b1     = (const float*)d_in[7];
  const float* W2     = (const float*)d_in[8];
  const float* b2     = (const float*)d_in[9];

  char* ws = (char*)d_ws;
  size_t off = 0;
  auto alloc = [&](size_t bytes) -> void* {
    void* p = ws + off;
    off += (bytes + 255) & ~(size_t)255;
    return p;
  };
  // total ws usage: ~40.5 MB
  u16* hbuf   = (u16*)alloc((size_t)2 * 32 * 512 * 2);  // 64 KB h double buffer
  u32* flags  = (u32*)alloc((size_t)64 * 128);          // 8 KB flag lines
  u16* Wenc_t = (u16*)alloc((size_t)512 * 256 * 2);     // [E][DIN]
  u16* Wih_t  = (u16*)alloc((size_t)2048 * 512 * 2);    // [4H][E]
  u16* Whh_t  = (u16*)alloc((size_t)2048 * 512 * 2);    // [4H][H]
  u16* W1_t   = (u16*)alloc((size_t)2048 * 512 * 2);    // [F][E]
  u16* W2_t   = (u16*)alloc((size_t)512 * 2048 * 2);    // [O][F]
  u16* big    = (u16*)alloc((size_t)8192 * 2048 * 2);   // 32 MB union: xbf | T chunk
  u16* xbf    = big;                                    // [B*S][256] (dead before T)
  u16* T      = big;                                    // [8192][2048] fc1 chunk

  // d_out is F32: ys[S*B*H] | h_n[B*H] | c_n[B*H] | embed_out[S*B*O]
  float* outp = (float*)d_out;
  float* hnp  = outp + (size_t)16777216;
  float* cnp  = hnp + 16384;
  float* eop  = cnp + 16384;               // f32 [32768][512]
  // emb (bf16, 33.5 MB) lives in the SECOND HALF of the embed_out region.
  // fc2 chunk c writes f32 bytes [16.78M*c, 16.78M*(c+1)) of the region;
  // fc1 chunk c reads emb bytes [33.55M + 8.39M*c, +8.39M) -- writes never
  // pass reads (16.78M*(c+1) <= 33.55M + 8.39M*(c+1) for c<=3).
  u16* emb  = (u16*)(eop + 8388608);

  // zero h double-buffer + flags (contiguous at ws start)
  hipMemsetAsync(ws, 0, (size_t)2 * 32 * 512 * 2 + (size_t)64 * 128, stream);

  // convert + transpose weights
  k_cast<<<8192, 256, 0, stream>>>(x, xbf, 2097152);
  k_transpose<<<dim3(8, 16), 256, 0, stream>>>(W_enc, Wenc_t, 256, 512);
  k_transpose<<<dim3(16, 64), 256, 0, stream>>>(W_ih, Wih_t, 512, 2048);
  k_transpose<<<dim3(16, 64), 256, 0, stream>>>(W_hh, Whh_t, 512, 2048);
  k_transpose<<<dim3(16, 64), 256, 0, stream>>>(W1, W1_t, 512, 2048);
  k_transpose<<<dim3(64, 16), 256, 0, stream>>>(W2, W2_t, 2048, 512);

  // encoder: emb[s*32+b][E] = x@W_enc + b_enc  (bf16 out, row remap)
  k_gemm<true, false, false><<<dim3(256, 4), 256, 0, stream>>>(
      xbf, Wenc_t, b_enc, emb, 32768, 512, 256);

  // recurrence (cooperative; fused x@W_ih, software-pipelined; f32 outputs)
  {
    void* args[] = {(void*)&Whh_t, (void*)&Wih_t, (void*)&emb, (void*)&b_lstm,
                    (void*)&hbuf, (void*)&outp, (void*)&hnp, (void*)&cnp, (void*)&flags};
    hipLaunchCooperativeKernel((const void*)k_lstm, dim3(64), dim3(256), args, 0, stream);
  }

  // MLP in 4 chunks of 8192 rows: fc1 -> T (bf16, ws), fc2 -> embed_out (f32)
  for (int cch = 0; cch < 4; cch++) {
    const u16* embc = emb + (size_t)cch * 8192 * 512;
    float* eoc = eop + (size_t)cch * 8192 * 512;
    k_gemm<false, true, false><<<dim3(64, 16), 256, 0, stream>>>(
        embc, W1_t, b1, T, 8192, 2048, 512);
    k_gemm<false, false, true><<<dim3(64, 4), 256, 0, stream>>>(
        T, W2_t, b2, eoc, 8192, 512, 2048);
  }
}